// Round 1
// baseline (992.250 us; speedup 1.0000x reference)
//
#include <hip/hip_runtime.h>
#include <hip/hip_bf16.h>

#define BATCH 8192
#define NVERT 778
#define NJ 16

static __device__ __forceinline__ unsigned short f2bf(float f) {
    unsigned int u = __float_as_uint(f);
    unsigned int r = (u + 0x7FFFu + ((u >> 16) & 1u)) >> 16;  // RNE
    return (unsigned short)r;
}
static __device__ __forceinline__ float bf2f(unsigned short s) {
    return __uint_as_float(((unsigned int)s) << 16);
}

// ---------------------------------------------------------------- K0: fold J_regressor
// JS[j][k][l] = sum_v Jreg[j,v]*shapedirs[v,k,l];  Jbase[j][k] = sum_v Jreg[j,v]*tmpl[v,k]
__global__ void k_pre(const float* __restrict__ tmpl, const float* __restrict__ shd,
                      const float* __restrict__ Jreg, float* __restrict__ JS,
                      float* __restrict__ Jb)
{
    int e = threadIdx.x;
    if (e < 480) {
        int j = e / 30, k = (e / 10) % 3, l = e % 10;
        float s = 0.0f;
        for (int v = 0; v < NVERT; ++v)
            s += Jreg[j * NVERT + v] * shd[v * 30 + k * 10 + l];
        JS[e] = s;
    } else if (e < 528) {
        int i = e - 480;
        int j = i / 3, k = i % 3;
        float s = 0.0f;
        for (int v = 0; v < NVERT; ++v)
            s += Jreg[j * NVERT + v] * tmpl[v * 3 + k];
        Jb[i] = s;
    }
}

// ---------------------------------------------------------------- K1: Rodrigues per (b,j)
__global__ __launch_bounds__(256) void k_rodr(const float* __restrict__ pose,
                                              float* __restrict__ rot)
{
    int t = blockIdx.x * 256 + threadIdx.x;
    if (t >= BATCH * NJ) return;
    int b = t >> 4, j = t & 15;
    const float* p = pose + b * 48 + j * 3;
    float x = p[0], y = p[1], z = p[2];
    float ax = x + 1e-8f, ay = y + 1e-8f, az = z + 1e-8f;
    float ang = sqrtf(ax * ax + ay * ay + az * az);
    float inv = 1.0f / ang;
    float a = x * inv, bb = y * inv, cc = z * inv;   // rot_dir = rot_vecs / angle
    float sn = sinf(ang), co = cosf(ang);
    float oc = 1.0f - co;
    float* R = rot + b * 144 + j * 9;
    R[0] = 1.0f - oc * (bb * bb + cc * cc);
    R[1] = -sn * cc + oc * a * bb;
    R[2] =  sn * bb + oc * a * cc;
    R[3] =  sn * cc + oc * a * bb;
    R[4] = 1.0f - oc * (a * a + cc * cc);
    R[5] = -sn * a + oc * bb * cc;
    R[6] = -sn * bb + oc * a * cc;
    R[7] =  sn * a + oc * bb * cc;
    R[8] = 1.0f - oc * (a * a + bb * bb);
}

// ---------------------------------------------------------------- K2: kinematic chain per b
// PARENTS = [0, 0,1,2, 0,4,5, 0,7,8, 0,10,11, 0,13,14] -> 5 chains of 3 off root
__global__ __launch_bounds__(256) void k_chain(
    const float* __restrict__ betas, const float* __restrict__ rot,
    const float* __restrict__ JS, const float* __restrict__ Jb,
    float* __restrict__ Abuf, float* __restrict__ jout)
{
    int b = blockIdx.x * 256 + threadIdx.x;
    if (b >= BATCH) return;
    float be[10];
#pragma unroll
    for (int l = 0; l < 10; ++l) be[l] = betas[b * 10 + l];

    const float* rb = rot + b * 144;
    float* Ab = Abuf + b * 192;
    float* jo = jout + b * 48;

    float j0[3];
#pragma unroll
    for (int k = 0; k < 3; ++k) {
        float s = Jb[k];
#pragma unroll
        for (int l = 0; l < 10; ++l) s += JS[k * 10 + l] * be[l];
        j0[k] = s;
    }
    float R0[9];
#pragma unroll
    for (int m = 0; m < 9; ++m) R0[m] = rb[m];

    // root: G0 = [R0 | j0];  A0 = [R0 | j0 - R0*j0]
#pragma unroll
    for (int r = 0; r < 3; ++r) {
        Ab[r * 4 + 0] = R0[r * 3 + 0];
        Ab[r * 4 + 1] = R0[r * 3 + 1];
        Ab[r * 4 + 2] = R0[r * 3 + 2];
        Ab[r * 4 + 3] = j0[r] - (R0[r * 3 + 0] * j0[0] + R0[r * 3 + 1] * j0[1] + R0[r * 3 + 2] * j0[2]);
        jo[r] = j0[r];
    }

#pragma unroll
    for (int c = 0; c < 5; ++c) {
        float Gp[12];
#pragma unroll
        for (int r = 0; r < 3; ++r) {
            Gp[r * 4 + 0] = R0[r * 3 + 0];
            Gp[r * 4 + 1] = R0[r * 3 + 1];
            Gp[r * 4 + 2] = R0[r * 3 + 2];
            Gp[r * 4 + 3] = j0[r];
        }
        float jp[3] = { j0[0], j0[1], j0[2] };
#pragma unroll
        for (int s3 = 0; s3 < 3; ++s3) {
            int j = 3 * c + 1 + s3;
            float jj[3];
#pragma unroll
            for (int k = 0; k < 3; ++k) {
                float s = Jb[j * 3 + k];
#pragma unroll
                for (int l = 0; l < 10; ++l) s += JS[(j * 3 + k) * 10 + l] * be[l];
                jj[k] = s;
            }
            float R[9];
#pragma unroll
            for (int m = 0; m < 9; ++m) R[m] = rb[j * 9 + m];
            float rel[3] = { jj[0] - jp[0], jj[1] - jp[1], jj[2] - jp[2] };
            float Gc[12];
#pragma unroll
            for (int r = 0; r < 3; ++r) {
#pragma unroll
                for (int cc = 0; cc < 3; ++cc)
                    Gc[r * 4 + cc] = Gp[r * 4 + 0] * R[cc] + Gp[r * 4 + 1] * R[3 + cc] + Gp[r * 4 + 2] * R[6 + cc];
                Gc[r * 4 + 3] = Gp[r * 4 + 0] * rel[0] + Gp[r * 4 + 1] * rel[1] + Gp[r * 4 + 2] * rel[2] + Gp[r * 4 + 3];
            }
#pragma unroll
            for (int r = 0; r < 3; ++r) {
                Ab[j * 12 + r * 4 + 0] = Gc[r * 4 + 0];
                Ab[j * 12 + r * 4 + 1] = Gc[r * 4 + 1];
                Ab[j * 12 + r * 4 + 2] = Gc[r * 4 + 2];
                Ab[j * 12 + r * 4 + 3] = Gc[r * 4 + 3] - (Gc[r * 4 + 0] * jj[0] + Gc[r * 4 + 1] * jj[1] + Gc[r * 4 + 2] * jj[2]);
                jo[j * 3 + r] = Gc[r * 4 + 3];
            }
#pragma unroll
            for (int m = 0; m < 12; ++m) Gp[m] = Gc[m];
            jp[0] = jj[0]; jp[1] = jj[1]; jp[2] = jj[2];
        }
    }
}

// ---------------------------------------------------------------- K3: fused vertex kernel
// tile: 32 batch x 32 vertices, 256 threads, 4 (b,v) pairs per thread (bv = tid&31)
__global__ __launch_bounds__(256) void k_verts(
    const float* __restrict__ betas, const float* __restrict__ tmpl,
    const float* __restrict__ shd, const float* __restrict__ posed,
    const float* __restrict__ wgt, const float* __restrict__ rot,
    const float* __restrict__ Abuf, float* __restrict__ out)
{
    __shared__ alignas(16) float A_s[32][192];            // 24576 B (broadcast reads)
    __shared__ alignas(16) float w_s[32][20];             //  2560 B (stride 20 -> b128 floor)
    __shared__ alignas(16) float betas_s[32][10];         //  1280 B
    __shared__ alignas(16) unsigned short pf_s[32][136];  //  8704 B bf16, [135] zero pad
    __shared__ alignas(16) unsigned short pd_s[3][32][140]; // 26880 B bf16 SoA-by-k, stride 140 -> 2-way

    const int tid = threadIdx.x;
    const int v0 = blockIdx.x * 32;
    const int b0 = blockIdx.y * 32;

    // ---- stage ----
    for (int e = tid; e < 32 * 192; e += 256)
        ((float*)A_s)[e] = Abuf[b0 * 192 + e];
    for (int e = tid; e < 32 * 16; e += 256) {
        int bvx = e >> 4, j = e & 15, v = v0 + bvx;
        w_s[bvx][j] = (v < NVERT) ? wgt[v * 16 + j] : 0.0f;
    }
    for (int e = tid; e < 32 * 10; e += 256) {
        int bm = e / 10, l = e % 10;
        betas_s[bm][l] = betas[(b0 + bm) * 10 + l];
    }
    for (int e = tid; e < 32 * 136; e += 256) {
        int bm = e / 136, f = e % 136;
        float val = 0.0f;
        if (f < 135) {
            int m9 = f % 9;
            float d = (m9 == 0 || m9 == 4 || m9 == 8) ? 1.0f : 0.0f;
            val = rot[(b0 + bm) * 144 + 9 + f] - d;   // pose_feature = R[1:] - I
        }
        pf_s[bm][f] = f2bf(val);
    }
    for (int e = tid; e < 135 * 96; e += 256) {
        int r = e / 96, c = e % 96;
        int bvx = c / 3, k = c % 3;
        int gcol = v0 * 3 + c;
        float val = (gcol < NVERT * 3) ? posed[r * (NVERT * 3) + gcol] : 0.0f;
        pd_s[k][bvx][r] = f2bf(val);
    }
    if (tid < 96) pd_s[tid >> 5][tid & 31][135] = 0;  // kill poison in the K-pad slot
    __syncthreads();

    const int bv = tid & 31;
    const int bmq = tid >> 5;            // 0..7 ; this thread's bm = bmq + 8c
    const int v = v0 + bv;
    const bool vok = (v < NVERT);

    // ---- v_shaped init: template + shapedirs . betas ----
    float acc[4][3];
    {
        float t0 = 0.f, t1 = 0.f, t2 = 0.f;
        float sh[30];
        if (vok) {
            t0 = tmpl[v * 3 + 0]; t1 = tmpl[v * 3 + 1]; t2 = tmpl[v * 3 + 2];
#pragma unroll
            for (int i = 0; i < 30; ++i) sh[i] = shd[v * 30 + i];
        } else {
#pragma unroll
            for (int i = 0; i < 30; ++i) sh[i] = 0.0f;
        }
#pragma unroll
        for (int c = 0; c < 4; ++c) {
            int bm = bmq + 8 * c;
            float a0 = t0, a1 = t1, a2 = t2;
#pragma unroll
            for (int l = 0; l < 10; ++l) {
                float be = betas_s[bm][l];
                a0 += be * sh[l];
                a1 += be * sh[10 + l];
                a2 += be * sh[20 + l];
            }
            acc[c][0] = a0; acc[c][1] = a1; acc[c][2] = a2;
        }
    }

    // ---- pose_offsets GEMM: acc += pf (1x135) . pd (135x3) ----
    for (int i = 0; i < 34; ++i) {
        float pd[3][4];
#pragma unroll
        for (int k = 0; k < 3; ++k) {
            ushort4 u = *(const ushort4*)&pd_s[k][bv][4 * i];
            pd[k][0] = bf2f(u.x); pd[k][1] = bf2f(u.y);
            pd[k][2] = bf2f(u.z); pd[k][3] = bf2f(u.w);
        }
#pragma unroll
        for (int c = 0; c < 4; ++c) {
            int bm = bmq + 8 * c;
            ushort4 u = *(const ushort4*)&pf_s[bm][4 * i];
            float p0 = bf2f(u.x), p1 = bf2f(u.y), p2 = bf2f(u.z), p3 = bf2f(u.w);
#pragma unroll
            for (int k = 0; k < 3; ++k)
                acc[c][k] += p0 * pd[k][0] + p1 * pd[k][1] + p2 * pd[k][2] + p3 * pd[k][3];
        }
    }

    // ---- LBS blend: out = sum_j w[v,j] * (A[b,j] . [v_posed,1]) ----
    float res[4][3];
#pragma unroll
    for (int c = 0; c < 4; ++c) res[c][0] = res[c][1] = res[c][2] = 0.0f;

#pragma unroll
    for (int j4 = 0; j4 < 4; ++j4) {
        float4 w4 = *(const float4*)&w_s[bv][4 * j4];
#pragma unroll
        for (int jjj = 0; jjj < 4; ++jjj) {
            int j = 4 * j4 + jjj;
            float w = (jjj == 0) ? w4.x : (jjj == 1) ? w4.y : (jjj == 2) ? w4.z : w4.w;
#pragma unroll
            for (int c = 0; c < 4; ++c) {
                int bm = bmq + 8 * c;
                const float4 r0 = *(const float4*)&A_s[bm][j * 12 + 0];
                const float4 r1 = *(const float4*)&A_s[bm][j * 12 + 4];
                const float4 r2 = *(const float4*)&A_s[bm][j * 12 + 8];
                float wx = w * acc[c][0], wy = w * acc[c][1], wz = w * acc[c][2];
                res[c][0] += r0.x * wx + r0.y * wy + r0.z * wz + r0.w * w;
                res[c][1] += r1.x * wx + r1.y * wy + r1.z * wz + r1.w * w;
                res[c][2] += r2.x * wx + r2.y * wy + r2.z * wz + r2.w * w;
            }
        }
    }

    if (vok) {
#pragma unroll
        for (int c = 0; c < 4; ++c) {
            int b = b0 + bmq + 8 * c;
            float* o = out + ((size_t)b * NVERT + v) * 3;
            o[0] = res[c][0]; o[1] = res[c][1]; o[2] = res[c][2];
        }
    }
}

// ----------------------------------------------------------------
extern "C" void kernel_launch(void* const* d_in, const int* in_sizes, int n_in,
                              void* d_out, int out_size, void* d_ws, size_t ws_size,
                              hipStream_t stream)
{
    (void)in_sizes; (void)n_in; (void)out_size; (void)ws_size;
    const float* betas = (const float*)d_in[0];
    const float* pose  = (const float*)d_in[1];
    const float* tmpl  = (const float*)d_in[2];
    const float* shd   = (const float*)d_in[3];
    const float* posed = (const float*)d_in[4];
    const float* Jreg  = (const float*)d_in[5];
    const float* wgt   = (const float*)d_in[6];
    // d_in[7] = parents (hard-coded in k_chain)
    float* out = (float*)d_out;

    char* ws = (char*)d_ws;
    float* JS   = (float*)(ws);                                   // 480 f
    float* Jb   = (float*)(ws + 1920);                            // 48 f
    float* rot  = (float*)(ws + 4096);                            // B*144 f
    float* Abuf = (float*)(ws + 4096 + (size_t)BATCH * 144 * 4);  // B*192 f
    float* jout = out + (size_t)BATCH * NVERT * 3;                // J_transformed

    k_pre<<<dim3(1), dim3(576), 0, stream>>>(tmpl, shd, Jreg, JS, Jb);
    k_rodr<<<dim3(BATCH * NJ / 256), dim3(256), 0, stream>>>(pose, rot);
    k_chain<<<dim3(BATCH / 256), dim3(256), 0, stream>>>(betas, rot, JS, Jb, Abuf, jout);
    k_verts<<<dim3((NVERT + 31) / 32, BATCH / 32), dim3(256), 0, stream>>>(
        betas, tmpl, shd, posed, wgt, rot, Abuf, out);
}

// Round 3
// 330.420 us; speedup vs baseline: 3.0030x; 3.0030x over previous
//
#include <hip/hip_runtime.h>
#include <hip/hip_bf16.h>

#define BATCH 8192
#define NVERT 778
#define NJ 16
#define KDIM 160      // 135 pose_feature + 10 betas + 1 const + 14 zero-pad
#define NPAD 2432     // 778*3 = 2334 -> 19*128

typedef __attribute__((ext_vector_type(8))) short short8v;
typedef __attribute__((ext_vector_type(4))) float f32x4;
typedef const __attribute__((address_space(1))) unsigned int* gas1_t;
typedef __attribute__((address_space(3))) unsigned int* las3_t;

static __device__ __forceinline__ unsigned short f2bf(float f) {
    unsigned int u = __float_as_uint(f);
    unsigned int r = (u + 0x7FFFu + ((u >> 16) & 1u)) >> 16;  // RNE
    return (unsigned short)r;
}
static __device__ __forceinline__ float bf2f(unsigned short s) {
    return __uint_as_float(((unsigned int)s) << 16);
}

// ---------------------------------------------------------------- K0: fold J_regressor
// one block (64 threads) per output dot-product of length 778
__global__ __launch_bounds__(64) void k_pre(const float* __restrict__ tmpl,
                                            const float* __restrict__ shd,
                                            const float* __restrict__ Jreg,
                                            float* __restrict__ JS,
                                            float* __restrict__ Jb)
{
    int e = blockIdx.x, l = threadIdx.x;
    float s = 0.0f;
    if (e < 480) {
        int j = e / 30, k = (e / 10) % 3, q = e % 10;
        for (int v = l; v < NVERT; v += 64) s += Jreg[j * NVERT + v] * shd[v * 30 + k * 10 + q];
    } else {
        int i = e - 480, j = i / 3, k = i % 3;
        for (int v = l; v < NVERT; v += 64) s += Jreg[j * NVERT + v] * tmpl[v * 3 + k];
    }
#pragma unroll
    for (int off = 32; off > 0; off >>= 1) s += __shfl_down(s, off, 64);
    if (l == 0) { if (e < 480) JS[e] = s; else Jb[e - 480] = s; }
}

// ---------------------------------------------------------------- K1: Rodrigues + X pack
__global__ __launch_bounds__(256) void k_rodr(const float* __restrict__ pose,
                                              const float* __restrict__ betas,
                                              float* __restrict__ rot,
                                              short* __restrict__ X)
{
    int t = blockIdx.x * 256 + threadIdx.x;
    if (t >= BATCH * NJ) return;
    int b = t >> 4, j = t & 15;
    const float* p = pose + b * 48 + j * 3;
    float x = p[0], y = p[1], z = p[2];
    float ax = x + 1e-8f, ay = y + 1e-8f, az = z + 1e-8f;
    float ang = sqrtf(ax * ax + ay * ay + az * az);
    float inv = 1.0f / ang;
    float a = x * inv, bb = y * inv, cc = z * inv;
    float sn = sinf(ang), co = cosf(ang);
    float oc = 1.0f - co;
    float R[9];
    R[0] = 1.0f - oc * (bb * bb + cc * cc);
    R[1] = -sn * cc + oc * a * bb;
    R[2] =  sn * bb + oc * a * cc;
    R[3] =  sn * cc + oc * a * bb;
    R[4] = 1.0f - oc * (a * a + cc * cc);
    R[5] = -sn * a + oc * bb * cc;
    R[6] = -sn * bb + oc * a * cc;
    R[7] =  sn * a + oc * bb * cc;
    R[8] = 1.0f - oc * (a * a + bb * bb);

    float* Rg = rot + b * 144 + j * 9;
#pragma unroll
    for (int m = 0; m < 9; ++m) Rg[m] = R[m];

    short* Xb = X + (size_t)b * KDIM;
    if (j > 0) {
        int base = (j - 1) * 9;
#pragma unroll
        for (int m = 0; m < 9; ++m) {
            float d = (m == 0 || m == 4 || m == 8) ? 1.0f : 0.0f;
            Xb[base + m] = (short)f2bf(R[m] - d);
        }
    } else {
#pragma unroll
        for (int l = 0; l < 10; ++l) Xb[135 + l] = (short)f2bf(betas[b * 10 + l]);
        Xb[145] = (short)0x3F80;  // 1.0 bf16
#pragma unroll
        for (int q = 146; q < 160; ++q) Xb[q] = 0;
    }
}

// ---------------------------------------------------------------- K2: kinematic chain per b
__global__ __launch_bounds__(64) void k_chain(
    const float* __restrict__ betas, const float* __restrict__ rot,
    const float* __restrict__ JS, const float* __restrict__ Jb,
    float* __restrict__ Abuf, float* __restrict__ jout)
{
    int b = blockIdx.x * 64 + threadIdx.x;
    if (b >= BATCH) return;
    float be[10];
#pragma unroll
    for (int l = 0; l < 10; ++l) be[l] = betas[b * 10 + l];

    const float* rb = rot + b * 144;
    float* Ab = Abuf + b * 192;
    float* jo = jout + b * 48;

    float j0[3];
#pragma unroll
    for (int k = 0; k < 3; ++k) {
        float s = Jb[k];
#pragma unroll
        for (int l = 0; l < 10; ++l) s += JS[k * 10 + l] * be[l];
        j0[k] = s;
    }
    float R0[9];
#pragma unroll
    for (int m = 0; m < 9; ++m) R0[m] = rb[m];

#pragma unroll
    for (int r = 0; r < 3; ++r) {
        Ab[r * 4 + 0] = R0[r * 3 + 0];
        Ab[r * 4 + 1] = R0[r * 3 + 1];
        Ab[r * 4 + 2] = R0[r * 3 + 2];
        Ab[r * 4 + 3] = j0[r] - (R0[r * 3 + 0] * j0[0] + R0[r * 3 + 1] * j0[1] + R0[r * 3 + 2] * j0[2]);
        jo[r] = j0[r];
    }

#pragma unroll
    for (int c = 0; c < 5; ++c) {
        float Gp[12];
#pragma unroll
        for (int r = 0; r < 3; ++r) {
            Gp[r * 4 + 0] = R0[r * 3 + 0];
            Gp[r * 4 + 1] = R0[r * 3 + 1];
            Gp[r * 4 + 2] = R0[r * 3 + 2];
            Gp[r * 4 + 3] = j0[r];
        }
        float jp[3] = { j0[0], j0[1], j0[2] };
#pragma unroll
        for (int s3 = 0; s3 < 3; ++s3) {
            int j = 3 * c + 1 + s3;
            float jj[3];
#pragma unroll
            for (int k = 0; k < 3; ++k) {
                float s = Jb[j * 3 + k];
#pragma unroll
                for (int l = 0; l < 10; ++l) s += JS[(j * 3 + k) * 10 + l] * be[l];
                jj[k] = s;
            }
            float R[9];
#pragma unroll
            for (int m = 0; m < 9; ++m) R[m] = rb[j * 9 + m];
            float rel[3] = { jj[0] - jp[0], jj[1] - jp[1], jj[2] - jp[2] };
            float Gc[12];
#pragma unroll
            for (int r = 0; r < 3; ++r) {
#pragma unroll
                for (int cc = 0; cc < 3; ++cc)
                    Gc[r * 4 + cc] = Gp[r * 4 + 0] * R[cc] + Gp[r * 4 + 1] * R[3 + cc] + Gp[r * 4 + 2] * R[6 + cc];
                Gc[r * 4 + 3] = Gp[r * 4 + 0] * rel[0] + Gp[r * 4 + 1] * rel[1] + Gp[r * 4 + 2] * rel[2] + Gp[r * 4 + 3];
            }
#pragma unroll
            for (int r = 0; r < 3; ++r) {
                Ab[j * 12 + r * 4 + 0] = Gc[r * 4 + 0];
                Ab[j * 12 + r * 4 + 1] = Gc[r * 4 + 1];
                Ab[j * 12 + r * 4 + 2] = Gc[r * 4 + 2];
                Ab[j * 12 + r * 4 + 3] = Gc[r * 4 + 3] - (Gc[r * 4 + 0] * jj[0] + Gc[r * 4 + 1] * jj[1] + Gc[r * 4 + 2] * jj[2]);
                jo[j * 3 + r] = Gc[r * 4 + 3];
            }
#pragma unroll
            for (int m = 0; m < 12; ++m) Gp[m] = Gc[m];
            jp[0] = jj[0]; jp[1] = jj[1]; jp[2] = jj[2];
        }
    }
}

// ---------------------------------------------------------------- K3: pack W^T [NPAD][KDIM] bf16
__global__ __launch_bounds__(256) void k_pack(const float* __restrict__ posed,
                                              const float* __restrict__ shd,
                                              const float* __restrict__ tmpl,
                                              short* __restrict__ Wt)
{
    int e = blockIdx.x * 256 + threadIdx.x;   // n*KDIM + k
    if (e >= NPAD * KDIM) return;
    int n = e / KDIM, k = e % KDIM;
    float val = 0.0f;
    if (n < NVERT * 3) {
        int v = n / 3, p = n % 3;
        if (k < 135)       val = posed[k * (NVERT * 3) + n];
        else if (k < 145)  val = shd[v * 30 + p * 10 + (k - 135)];
        else if (k == 145) val = tmpl[n];
    }
    Wt[e] = (short)f2bf(val);
}

// ---------------------------------------------------------------- K4: MFMA GEMM -> v_posed bf16
// tile 64(M=batch) x 128(N=vert*3), K=160 staged whole. LDS K-sliced [kg][row][8].
__global__ __launch_bounds__(256) void k_gemm(const short* __restrict__ X,
                                              const short* __restrict__ Wt,
                                              short* __restrict__ vp)
{
    __shared__ short Xs[20 * 64 * 8];    // 20 KB
    __shared__ short Ws[20 * 128 * 8];   // 40 KB

    const int tid = threadIdx.x;
    const int w = tid >> 6, lane = tid & 63;
    const int b0 = blockIdx.x * 64;
    const int n0 = blockIdx.y * 128;

    // stage X tile (1280 16B chunks) and Wt tile (2560 chunks) via global_load_lds
    for (int c0 = w * 64; c0 < 1280; c0 += 256) {
        int c = c0 + lane;
        const short* src = X + (size_t)(b0 + (c & 63)) * KDIM + (c >> 6) * 8;
        __builtin_amdgcn_global_load_lds((gas1_t)(const void*)src,
                                         (las3_t)(void*)((char*)Xs + c0 * 16), 16, 0, 0);
    }
    for (int c0 = w * 64; c0 < 2560; c0 += 256) {
        int c = c0 + lane;
        const short* src = Wt + (size_t)(n0 + (c & 127)) * KDIM + (c >> 7) * 8;
        __builtin_amdgcn_global_load_lds((gas1_t)(const void*)src,
                                         (las3_t)(void*)((char*)Ws + c0 * 16), 16, 0, 0);
    }
    __syncthreads();

    const int lm = lane & 15, lk = lane >> 4;
    const int wm = w >> 1, wn = w & 1;

    f32x4 acc[2][4];
#pragma unroll
    for (int mi = 0; mi < 2; ++mi)
#pragma unroll
        for (int ni = 0; ni < 4; ++ni)
            acc[mi][ni] = (f32x4){0.0f, 0.0f, 0.0f, 0.0f};

#pragma unroll
    for (int ks = 0; ks < 5; ++ks) {
        short8v a[2], bf[4];
#pragma unroll
        for (int mi = 0; mi < 2; ++mi)
            a[mi] = *(const short8v*)&Xs[((ks * 4 + lk) * 64 + wm * 32 + mi * 16 + lm) * 8];
#pragma unroll
        for (int ni = 0; ni < 4; ++ni)
            bf[ni] = *(const short8v*)&Ws[((ks * 4 + lk) * 128 + wn * 64 + ni * 16 + lm) * 8];
#pragma unroll
        for (int mi = 0; mi < 2; ++mi)
#pragma unroll
            for (int ni = 0; ni < 4; ++ni)
                acc[mi][ni] = __builtin_amdgcn_mfma_f32_16x16x32_bf16(a[mi], bf[ni], acc[mi][ni], 0, 0, 0);
    }

#pragma unroll
    for (int mi = 0; mi < 2; ++mi) {
        int row0 = b0 + wm * 32 + mi * 16 + lk * 4;
#pragma unroll
        for (int ni = 0; ni < 4; ++ni) {
            int col = n0 + wn * 64 + ni * 16 + lm;
#pragma unroll
            for (int r = 0; r < 4; ++r)
                vp[(size_t)(row0 + r) * NPAD + col] = (short)f2bf(acc[mi][ni][r]);
        }
    }
}

// ---------------------------------------------------------------- K5: LBS blend
// block: 4 batches (1 per wave) x 256 verts (4 per lane). A reads = LDS broadcast.
__global__ __launch_bounds__(256) void k_lbs(const short* __restrict__ vp,
                                             const float* __restrict__ Abuf,
                                             const float* __restrict__ wgt,
                                             float* __restrict__ out)
{
    __shared__ float A_s[4 * 192];
    __shared__ float w_sT[16 * 257];   // transposed, stride 257 -> conflict-free

    const int tid = threadIdx.x;
    const int bg = blockIdx.x;
    const int v0 = blockIdx.y * 256;

    for (int e = tid; e < 768; e += 256) A_s[e] = Abuf[(size_t)bg * 768 + e];
    for (int e = tid; e < 4096; e += 256) {
        int j = e & 15, vi = e >> 4, v = v0 + vi;
        w_sT[j * 257 + vi] = (v < NVERT) ? wgt[v * 16 + j] : 0.0f;
    }
    __syncthreads();

    const int wv = tid >> 6, l = tid & 63;
    const int b = bg * 4 + wv;
    const size_t vprow = (size_t)b * NPAD;

    float h[4][3];
    int vok = 0;
#pragma unroll
    for (int i = 0; i < 4; ++i) {
        int v = v0 + l + 64 * i;
        if (v < NVERT) {
            vok |= 1 << i;
            h[i][0] = bf2f((unsigned short)vp[vprow + 3 * v + 0]);
            h[i][1] = bf2f((unsigned short)vp[vprow + 3 * v + 1]);
            h[i][2] = bf2f((unsigned short)vp[vprow + 3 * v + 2]);
        } else {
            h[i][0] = h[i][1] = h[i][2] = 0.0f;
        }
    }

    float o[4][3];
#pragma unroll
    for (int i = 0; i < 4; ++i) o[i][0] = o[i][1] = o[i][2] = 0.0f;

#pragma unroll
    for (int j = 0; j < 16; ++j) {
        const float4 r0 = *(const float4*)&A_s[wv * 192 + j * 12 + 0];
        const float4 r1 = *(const float4*)&A_s[wv * 192 + j * 12 + 4];
        const float4 r2 = *(const float4*)&A_s[wv * 192 + j * 12 + 8];
#pragma unroll
        for (int i = 0; i < 4; ++i) {
            float wj = w_sT[j * 257 + l + 64 * i];
            float tx = fmaf(r0.x, h[i][0], fmaf(r0.y, h[i][1], fmaf(r0.z, h[i][2], r0.w)));
            float ty = fmaf(r1.x, h[i][0], fmaf(r1.y, h[i][1], fmaf(r1.z, h[i][2], r1.w)));
            float tz = fmaf(r2.x, h[i][0], fmaf(r2.y, h[i][1], fmaf(r2.z, h[i][2], r2.w)));
            o[i][0] = fmaf(wj, tx, o[i][0]);
            o[i][1] = fmaf(wj, ty, o[i][1]);
            o[i][2] = fmaf(wj, tz, o[i][2]);
        }
    }

#pragma unroll
    for (int i = 0; i < 4; ++i) {
        int v = v0 + l + 64 * i;
        if (vok & (1 << i)) {
            float* op = out + ((size_t)b * NVERT + v) * 3;
            op[0] = o[i][0]; op[1] = o[i][1]; op[2] = o[i][2];
        }
    }
}

// ----------------------------------------------------------------
extern "C" void kernel_launch(void* const* d_in, const int* in_sizes, int n_in,
                              void* d_out, int out_size, void* d_ws, size_t ws_size,
                              hipStream_t stream)
{
    (void)in_sizes; (void)n_in; (void)out_size; (void)ws_size;
    const float* betas = (const float*)d_in[0];
    const float* pose  = (const float*)d_in[1];
    const float* tmpl  = (const float*)d_in[2];
    const float* shd   = (const float*)d_in[3];
    const float* posed = (const float*)d_in[4];
    const float* Jreg  = (const float*)d_in[5];
    const float* wgt   = (const float*)d_in[6];
    float* out = (float*)d_out;

    char* ws = (char*)d_ws;
    float* JS   = (float*)(ws);                 // 480 f32
    float* Jb   = (float*)(ws + 1920);          // 48 f32
    short* Wt   = (short*)(ws + 4096);          // [2432][160] bf16  (778240 B)
    short* X    = (short*)(ws + 786432);        // [8192][160] bf16  (2621440 B)
    float* rot  = (float*)(ws + 3407872);       // [8192][144] f32   (4718592 B)
    float* Abuf = (float*)(ws + 8126464);       // [8192][192] f32   (6291456 B)
    short* vp   = (short*)(ws + 14417920);      // [8192][2432] bf16 (39845888 B) -> end 54263808
    float* jout = out + (size_t)BATCH * NVERT * 3;

    k_pre <<<528, 64, 0, stream>>>(tmpl, shd, Jreg, JS, Jb);
    k_rodr<<<BATCH * NJ / 256, 256, 0, stream>>>(pose, betas, rot, X);
    k_pack<<<(NPAD * KDIM + 255) / 256, 256, 0, stream>>>(posed, shd, tmpl, Wt);
    k_chain<<<BATCH / 64, 64, 0, stream>>>(betas, rot, JS, Jb, Abuf, jout);
    k_gemm<<<dim3(BATCH / 64, NPAD / 128), 256, 0, stream>>>(X, Wt, vp);
    k_lbs <<<dim3(BATCH / 4, 4), 256, 0, stream>>>(vp, Abuf, wgt, out);
}

// Round 7
// 183.204 us; speedup vs baseline: 5.4161x; 1.8036x over previous
//
#include <hip/hip_runtime.h>
#include <hip/hip_bf16.h>

#define BATCH 8192
#define NVERT 778
#define NVP   832     // vertex pad: 13 tiles of 64
#define NJ 16
#define KDIM 160      // 135 pose_feature + 10 betas + 1 const + 14 zero-pad
#define ASTR 196      // Abuf row stride in floats (192 used + 4 pad) = 49 x 16B chunks

typedef __attribute__((ext_vector_type(8))) short short8v;
typedef __attribute__((ext_vector_type(4))) float f32x4;
typedef const __attribute__((address_space(1))) unsigned int* gas1_t;
typedef __attribute__((address_space(3))) unsigned int* las3_t;

static __device__ __forceinline__ unsigned short f2bf(float f) {
    unsigned int u = __float_as_uint(f);
    unsigned int r = (u + 0x7FFFu + ((u >> 16) & 1u)) >> 16;  // RNE
    return (unsigned short)r;
}

// ---------------------------------------------------------------- K0: fold J_regressor
__global__ __launch_bounds__(64) void k_pre(const float* __restrict__ tmpl,
                                            const float* __restrict__ shd,
                                            const float* __restrict__ Jreg,
                                            float* __restrict__ JS,
                                            float* __restrict__ Jb)
{
    int e = blockIdx.x, l = threadIdx.x;
    float s = 0.0f;
    if (e < 480) {
        int j = e / 30, k = (e / 10) % 3, q = e % 10;
        for (int v = l; v < NVERT; v += 64) s += Jreg[j * NVERT + v] * shd[v * 30 + k * 10 + q];
    } else {
        int i = e - 480, j = i / 3, k = i % 3;
        for (int v = l; v < NVERT; v += 64) s += Jreg[j * NVERT + v] * tmpl[v * 3 + k];
    }
#pragma unroll
    for (int off = 32; off > 0; off >>= 1) s += __shfl_down(s, off, 64);
    if (l == 0) { if (e < 480) JS[e] = s; else Jb[e - 480] = s; }
}

// ---------------------------------------------------------------- K1: Rodrigues + X pack
__global__ __launch_bounds__(256) void k_rodr(const float* __restrict__ pose,
                                              const float* __restrict__ betas,
                                              float* __restrict__ rot,
                                              short* __restrict__ X)
{
    int t = blockIdx.x * 256 + threadIdx.x;
    if (t >= BATCH * NJ) return;
    int b = t >> 4, j = t & 15;
    const float* p = pose + b * 48 + j * 3;
    float x = p[0], y = p[1], z = p[2];
    float ax = x + 1e-8f, ay = y + 1e-8f, az = z + 1e-8f;
    float ang = sqrtf(ax * ax + ay * ay + az * az);
    float inv = 1.0f / ang;
    float a = x * inv, bb = y * inv, cc = z * inv;
    float sn = sinf(ang), co = cosf(ang);
    float oc = 1.0f - co;
    float R[9];
    R[0] = 1.0f - oc * (bb * bb + cc * cc);
    R[1] = -sn * cc + oc * a * bb;
    R[2] =  sn * bb + oc * a * cc;
    R[3] =  sn * cc + oc * a * bb;
    R[4] = 1.0f - oc * (a * a + cc * cc);
    R[5] = -sn * a + oc * bb * cc;
    R[6] = -sn * bb + oc * a * cc;
    R[7] =  sn * a + oc * bb * cc;
    R[8] = 1.0f - oc * (a * a + bb * bb);

    float* Rg = rot + b * 144 + j * 9;
#pragma unroll
    for (int m = 0; m < 9; ++m) Rg[m] = R[m];

    short* Xb = X + (size_t)b * KDIM;
    if (j > 0) {
        int base = (j - 1) * 9;
#pragma unroll
        for (int m = 0; m < 9; ++m) {
            float d = (m == 0 || m == 4 || m == 8) ? 1.0f : 0.0f;
            Xb[base + m] = (short)f2bf(R[m] - d);
        }
    } else {
#pragma unroll
        for (int l = 0; l < 10; ++l) Xb[135 + l] = (short)f2bf(betas[b * 10 + l]);
        Xb[145] = (short)0x3F80;  // 1.0 bf16
#pragma unroll
        for (int q = 146; q < 160; ++q) Xb[q] = 0;
    }
}

// ---------------------------------------------------------------- K2: kinematic chain per b
__global__ __launch_bounds__(64) void k_chain(
    const float* __restrict__ betas, const float* __restrict__ rot,
    const float* __restrict__ JS, const float* __restrict__ Jb,
    float* __restrict__ Abuf, float* __restrict__ jout)
{
    int b = blockIdx.x * 64 + threadIdx.x;
    if (b >= BATCH) return;
    float be[10];
#pragma unroll
    for (int l = 0; l < 10; ++l) be[l] = betas[b * 10 + l];

    const float* rb = rot + b * 144;
    float* Ab = Abuf + (size_t)b * ASTR;
    float* jo = jout + b * 48;

    float j0[3];
#pragma unroll
    for (int k = 0; k < 3; ++k) {
        float s = Jb[k];
#pragma unroll
        for (int l = 0; l < 10; ++l) s += JS[k * 10 + l] * be[l];
        j0[k] = s;
    }
    float R0[9];
#pragma unroll
    for (int m = 0; m < 9; ++m) R0[m] = rb[m];

#pragma unroll
    for (int r = 0; r < 3; ++r) {
        Ab[r * 4 + 0] = R0[r * 3 + 0];
        Ab[r * 4 + 1] = R0[r * 3 + 1];
        Ab[r * 4 + 2] = R0[r * 3 + 2];
        Ab[r * 4 + 3] = j0[r] - (R0[r * 3 + 0] * j0[0] + R0[r * 3 + 1] * j0[1] + R0[r * 3 + 2] * j0[2]);
        jo[r] = j0[r];
    }

#pragma unroll
    for (int c = 0; c < 5; ++c) {
        float Gp[12];
#pragma unroll
        for (int r = 0; r < 3; ++r) {
            Gp[r * 4 + 0] = R0[r * 3 + 0];
            Gp[r * 4 + 1] = R0[r * 3 + 1];
            Gp[r * 4 + 2] = R0[r * 3 + 2];
            Gp[r * 4 + 3] = j0[r];
        }
        float jp[3] = { j0[0], j0[1], j0[2] };
#pragma unroll
        for (int s3 = 0; s3 < 3; ++s3) {
            int j = 3 * c + 1 + s3;
            float jj[3];
#pragma unroll
            for (int k = 0; k < 3; ++k) {
                float s = Jb[j * 3 + k];
#pragma unroll
                for (int l = 0; l < 10; ++l) s += JS[(j * 3 + k) * 10 + l] * be[l];
                jj[k] = s;
            }
            float R[9];
#pragma unroll
            for (int m = 0; m < 9; ++m) R[m] = rb[j * 9 + m];
            float rel[3] = { jj[0] - jp[0], jj[1] - jp[1], jj[2] - jp[2] };
            float Gc[12];
#pragma unroll
            for (int r = 0; r < 3; ++r) {
#pragma unroll
                for (int cc = 0; cc < 3; ++cc)
                    Gc[r * 4 + cc] = Gp[r * 4 + 0] * R[cc] + Gp[r * 4 + 1] * R[3 + cc] + Gp[r * 4 + 2] * R[6 + cc];
                Gc[r * 4 + 3] = Gp[r * 4 + 0] * rel[0] + Gp[r * 4 + 1] * rel[1] + Gp[r * 4 + 2] * rel[2] + Gp[r * 4 + 3];
            }
#pragma unroll
            for (int r = 0; r < 3; ++r) {
                Ab[j * 12 + r * 4 + 0] = Gc[r * 4 + 0];
                Ab[j * 12 + r * 4 + 1] = Gc[r * 4 + 1];
                Ab[j * 12 + r * 4 + 2] = Gc[r * 4 + 2];
                Ab[j * 12 + r * 4 + 3] = Gc[r * 4 + 3] - (Gc[r * 4 + 0] * jj[0] + Gc[r * 4 + 1] * jj[1] + Gc[r * 4 + 2] * jj[2]);
                jo[j * 3 + r] = Gc[r * 4 + 3];
            }
#pragma unroll
            for (int m = 0; m < 12; ++m) Gp[m] = Gc[m];
            jp[0] = jj[0]; jp[1] = jj[1]; jp[2] = jj[2];
        }
    }
}

// ---------------------------------------------------------------- K3: pack Wt3 [3][NVP][KDIM] bf16
__global__ __launch_bounds__(256) void k_pack3(const float* __restrict__ posed,
                                               const float* __restrict__ shd,
                                               const float* __restrict__ tmpl,
                                               short* __restrict__ Wt3)
{
    int e = blockIdx.x * 256 + threadIdx.x;   // ((p*NVP + v)*KDIM + k)
    if (e >= 3 * NVP * KDIM) return;
    int k = e % KDIM, pv = e / KDIM;
    int v = pv % NVP, p = pv / NVP;
    float val = 0.0f;
    if (v < NVERT) {
        int n = v * 3 + p;
        if (k < 135)       val = posed[(size_t)k * (NVERT * 3) + n];
        else if (k < 145)  val = shd[v * 30 + p * 10 + (k - 135)];
        else if (k == 145) val = tmpl[n];
    }
    Wt3[e] = (short)f2bf(val);
}

// ---------------------------------------------------------------- K4: fused MFMA GEMM + LBS
// tile: 64 batches x 64 verts x 3 planes. 4 waves, wave wid owns rows wid*16..+15.
// LDS phase union: ph1 {Xs[20][64][8], Ws[3][20][64][8]} 80KB; ph2 {A_s[64][196], w_s[64][17]} 54KB.
__global__ __launch_bounds__(256, 2) void k_fused(
    const short* __restrict__ X, const short* __restrict__ Wt3,
    const float* __restrict__ Abuf, const float* __restrict__ wgt,
    float* __restrict__ out)
{
    __shared__ __attribute__((aligned(16))) char smem[81920];
    short* Xs  = (short*)smem;                 // ph1: chunks 0..1279
    short* Ws  = (short*)(smem + 20480);       // ph1: chunks 1280..5119 (contiguous with Xs)
    float* A_s = (float*)smem;                 // ph2: [64][196]
    float* w_s = (float*)(smem + 50176);       // ph2: [64][17]

    const int tid = threadIdx.x;
    const int wid = tid >> 6, lane = tid & 63;
    const int lm = lane & 15, lk = lane >> 4;
    const int v0 = blockIdx.x * 64;
    const int b0 = blockIdx.y * 64;

    // ---- phase 1 staging: X tile + Wt3 tile, dest = chunk c * 16B (linear) ----
    for (int c0 = wid * 64; c0 < 5120; c0 += 256) {
        int c = c0 + lane;
        const short* src;
        if (c < 1280) {
            src = X + (size_t)(b0 + (c & 63)) * KDIM + (c >> 6) * 8;
        } else {
            int cw = c - 1280;                  // ((p*20 + kg)*64 + row)
            int row = cw & 63, kgp = cw >> 6;   // kgp = p*20 + kg
            int kg = kgp % 20, p = kgp / 20;
            src = Wt3 + ((size_t)(p * NVP + v0 + row)) * KDIM + kg * 8;
        }
        __builtin_amdgcn_global_load_lds((gas1_t)(const void*)src,
                                         (las3_t)(void*)(smem + c0 * 16), 16, 0, 0);
    }
    __syncthreads();

    // ---- MFMA: acc[p][vi] over K=160 (5 ks-steps of 32) ----
    f32x4 acc[3][4];
#pragma unroll
    for (int p = 0; p < 3; ++p)
#pragma unroll
        for (int vi = 0; vi < 4; ++vi)
            acc[p][vi] = (f32x4){0.0f, 0.0f, 0.0f, 0.0f};

#pragma unroll
    for (int ks = 0; ks < 5; ++ks) {
        int kg = ks * 4 + lk;
        short8v a = *(const short8v*)&Xs[(kg * 64 + wid * 16 + lm) * 8];
        short8v bf[3][4];
#pragma unroll
        for (int p = 0; p < 3; ++p)
#pragma unroll
            for (int vi = 0; vi < 4; ++vi)
                bf[p][vi] = *(const short8v*)&Ws[((p * 20 + kg) * 64 + vi * 16 + lm) * 8];
#pragma unroll
        for (int p = 0; p < 3; ++p)
#pragma unroll
            for (int vi = 0; vi < 4; ++vi)
                acc[p][vi] = __builtin_amdgcn_mfma_f32_16x16x32_bf16(a, bf[p][vi], acc[p][vi], 0, 0, 0);
    }
    __syncthreads();   // all waves done reading Xs/Ws before overwrite

    // ---- phase 2 staging: A rows (3136 chunks of 16B, linear dest) + weights ----
    for (int c0 = wid * 64; c0 < 3136; c0 += 256) {
        int c = c0 + lane;
        const float* src = Abuf + (size_t)(b0 + c / 49) * ASTR + (c % 49) * 4;
        __builtin_amdgcn_global_load_lds((gas1_t)(const void*)src,
                                         (las3_t)(void*)(smem + c0 * 16), 16, 0, 0);
    }
    for (int e = tid; e < 64 * 17; e += 256) {
        int vi = e / 17, jj = e % 17;
        float val = (jj < 16 && (v0 + vi) < NVERT) ? wgt[(v0 + vi) * 16 + jj] : 0.0f;
        w_s[e] = val;
    }
    __syncthreads();

    // ---- LBS blend in f32: o[r][vi][p] = sum_j w[v,j] * (A[b,j] . [h,1]) ----
    float o[4][4][3];
#pragma unroll
    for (int r = 0; r < 4; ++r)
#pragma unroll
        for (int vi = 0; vi < 4; ++vi)
            o[r][vi][0] = o[r][vi][1] = o[r][vi][2] = 0.0f;

    for (int j = 0; j < 16; ++j) {
        float wj[4];
#pragma unroll
        for (int vi = 0; vi < 4; ++vi) wj[vi] = w_s[(vi * 16 + lm) * 17 + j];
#pragma unroll
        for (int r = 0; r < 4; ++r) {
            const float* Ar = &A_s[(wid * 16 + lk * 4 + r) * ASTR + j * 12];
            f32x4 R0 = *(const f32x4*)(Ar);
            f32x4 R1 = *(const f32x4*)(Ar + 4);
            f32x4 R2 = *(const f32x4*)(Ar + 8);
#pragma unroll
            for (int vi = 0; vi < 4; ++vi) {
                float x = acc[0][vi][r], y = acc[1][vi][r], z = acc[2][vi][r];
                float t0 = fmaf(R0[0], x, fmaf(R0[1], y, fmaf(R0[2], z, R0[3])));
                float t1 = fmaf(R1[0], x, fmaf(R1[1], y, fmaf(R1[2], z, R1[3])));
                float t2 = fmaf(R2[0], x, fmaf(R2[1], y, fmaf(R2[2], z, R2[3])));
                o[r][vi][0] = fmaf(wj[vi], t0, o[r][vi][0]);
                o[r][vi][1] = fmaf(wj[vi], t1, o[r][vi][1]);
                o[r][vi][2] = fmaf(wj[vi], t2, o[r][vi][2]);
            }
        }
    }

    // ---- store ----
#pragma unroll
    for (int r = 0; r < 4; ++r) {
        int b = b0 + wid * 16 + lk * 4 + r;
#pragma unroll
        for (int vi = 0; vi < 4; ++vi) {
            int v = v0 + vi * 16 + lm;
            if (v < NVERT) {
                float* op = out + ((size_t)b * NVERT + v) * 3;
                op[0] = o[r][vi][0]; op[1] = o[r][vi][1]; op[2] = o[r][vi][2];
            }
        }
    }
}

// ----------------------------------------------------------------
extern "C" void kernel_launch(void* const* d_in, const int* in_sizes, int n_in,
                              void* d_out, int out_size, void* d_ws, size_t ws_size,
                              hipStream_t stream)
{
    (void)in_sizes; (void)n_in; (void)out_size; (void)ws_size;
    const float* betas = (const float*)d_in[0];
    const float* pose  = (const float*)d_in[1];
    const float* tmpl  = (const float*)d_in[2];
    const float* shd   = (const float*)d_in[3];
    const float* posed = (const float*)d_in[4];
    const float* Jreg  = (const float*)d_in[5];
    const float* wgt   = (const float*)d_in[6];
    float* out = (float*)d_out;

    char* ws = (char*)d_ws;
    float* JS   = (float*)(ws);                 // 480 f32
    float* Jb   = (float*)(ws + 1920);          // 48 f32
    short* X    = (short*)(ws + 4096);          // [8192][160] bf16   -> 2,621,440 B
    float* rot  = (float*)(ws + 2625536);       // [8192][144] f32    -> 4,718,592 B
    short* Wt3  = (short*)(ws + 7344128);       // [3][832][160] bf16 ->   798,720 B
    float* Abuf = (float*)(ws + 8142848);       // [8192][196] f32    -> 6,422,528 B (end 14,565,376)
    float* jout = out + (size_t)BATCH * NVERT * 3;

    k_pre  <<<528, 64, 0, stream>>>(tmpl, shd, Jreg, JS, Jb);
    k_rodr <<<BATCH * NJ / 256, 256, 0, stream>>>(pose, betas, rot, X);
    k_pack3<<<(3 * NVP * KDIM) / 256, 256, 0, stream>>>(posed, shd, tmpl, Wt3);
    k_chain<<<BATCH / 64, 64, 0, stream>>>(betas, rot, JS, Jb, Abuf, jout);
    k_fused<<<dim3(NVP / 64, BATCH / 64), 256, 0, stream>>>(X, Wt3, Abuf, wgt, out);
}